// Round 9
// baseline (1227.547 us; speedup 1.0000x reference)
//
#include <hip/hip_runtime.h>
#include <hip/hip_bf16.h>
#include <math.h>

#define B_  16
#define S_  512
#define D_  512
#define H_  8
#define DK_ 64
#define F_  2048
#define NQ_ 8

typedef float f4 __attribute__((ext_vector_type(4)));

// ---------------------------------------------------------------------------
// embedding + sinusoidal positional encoding
// grid: B*S blocks, 128 threads (4 floats/thread)
__global__ __launch_bounds__(128) void k_embed(const int* __restrict__ tok,
                                               const float* __restrict__ emb,
                                               float* __restrict__ x) {
    int row = blockIdx.x;            // b*S + s
    int s   = row & (S_ - 1);
    int t   = tok[row];
    int d0  = threadIdx.x << 2;
    f4 v = *reinterpret_cast<const f4*>(emb + (size_t)t * D_ + d0);
    #pragma unroll
    for (int e = 0; e < 4; ++e) {
        int d = d0 + e;
        float freq = expf(-(float)(d & ~1) * (9.210340371976184f / 512.f));
        float arg  = (float)s * freq;
        v[e] += (d & 1) ? cosf(arg) : sinf(arg);
    }
    *reinterpret_cast<f4*>(x + (size_t)row * D_ + d0) = v;
}

// ---------------------------------------------------------------------------
// flash attention per (b, h, q-tile of 64). scores = Xh Xh^T / 8, softmax, @Xh.
// LDS: XKT[d][k] transposed k-tile (128 k), QT[d][q], P[q][k]; all chunk-XOR
// swizzled so the hot reads are <=2-way bank conflicts. Exactly 64 KiB.
// BUGFIX (r2): sub-tile offset within an XKT row is `ks` ELEMENTS (64), not
// (ks<<2)=256 — the old code read K/V from the wrong d-rows for sub==1
// (half of all keys), a deterministic 15%-of-scale error.
__global__ __launch_bounds__(256, 2) void k_attn(const float* __restrict__ x,
                                                 float* __restrict__ y) {
    __shared__ __align__(16) float QT [DK_ * 64];   // 16 KiB
    __shared__ __align__(16) float XKT[DK_ * 128];  // 32 KiB
    __shared__ __align__(16) float Psh[64 * 64];    // 16 KiB

    const int tid = threadIdx.x;
    const int tx  = tid & 15;        // k (scores) / d (PV) tile col group
    const int ty  = tid >> 4;        // q tile row group
    const int qt0 = blockIdx.x << 6;
    const int h   = blockIdx.y, b = blockIdx.z;
    const float* xb = x + (size_t)b * S_ * D_ + h * DK_;   // row stride D_

    // stage Q tile transposed: QT[d][q], swizzle key2(d) = (d ^ (d>>2)) & 3
    {
        int c = tid & 15, r = tid >> 4;
        #pragma unroll
        for (int p = 0; p < 4; ++p) {
            int q = p * 16 + r;
            f4 v = *reinterpret_cast<const f4*>(xb + (size_t)(qt0 + q) * D_ + (c << 2));
            #pragma unroll
            for (int e = 0; e < 4; ++e) {
                int d = (c << 2) + e;
                int key = (d ^ (d >> 2)) & 3;
                QT[(d << 6) + ((((q >> 2) ^ key) << 2) | (q & 3))] = v[e];
            }
        }
    }

    float o[4][4] = {};
    float m_i[4], l_i[4];
    #pragma unroll
    for (int i = 0; i < 4; ++i) { m_i[i] = -INFINITY; l_i[i] = 0.f; }

    for (int k0 = 0; k0 < S_; k0 += 128) {
        __syncthreads();                      // prior PV done with XKT
        // stage K tile transposed: XKT[d][kk], key3(d) = (d ^ (d>>2)) & 7
        {
            int c = tid & 15, r = tid >> 4;
            #pragma unroll
            for (int p = 0; p < 8; ++p) {
                int kk = p * 16 + r;
                f4 v = *reinterpret_cast<const f4*>(xb + (size_t)(k0 + kk) * D_ + (c << 2));
                #pragma unroll
                for (int e = 0; e < 4; ++e) {
                    int d = (c << 2) + e;
                    int key = (d ^ (d >> 2)) & 7;
                    XKT[(d << 7) + ((((kk >> 2) ^ key) << 2) | (kk & 3))] = v[e];
                }
            }
        }
        __syncthreads();

        #pragma unroll
        for (int sub = 0; sub < 2; ++sub) {
            const int ks = sub << 6;          // element offset 0 or 64 within row
            // ---- scores tile 64q x 64k, 4x4 per thread ----
            float s[4][4] = {};
            #pragma unroll 8
            for (int d = 0; d < 64; ++d) {
                int keyq = (d ^ (d >> 2)) & 3;
                int keyk = (d ^ (d >> 2)) & 7;
                f4 aq = *reinterpret_cast<const f4*>(&QT [(d << 6) + ((ty ^ keyq) << 2)]);
                f4 bk = *reinterpret_cast<const f4*>(&XKT[(d << 7) + ks + ((tx ^ keyk) << 2)]);
                #pragma unroll
                for (int i = 0; i < 4; ++i)
                    #pragma unroll
                    for (int j = 0; j < 4; ++j) s[i][j] += aq[i] * bk[j];
            }
            // ---- online softmax (row groups share ty; reduce over 16 tx lanes) ----
            float p[4][4];
            #pragma unroll
            for (int i = 0; i < 4; ++i) {
                #pragma unroll
                for (int j = 0; j < 4; ++j) s[i][j] *= 0.125f;   // 1/sqrt(dk)
                float mm = fmaxf(fmaxf(s[i][0], s[i][1]), fmaxf(s[i][2], s[i][3]));
                #pragma unroll
                for (int off = 1; off < 16; off <<= 1) mm = fmaxf(mm, __shfl_xor(mm, off));
                float mn = fmaxf(m_i[i], mm);
                float sc = expf(m_i[i] - mn);   // == 1.0f exactly when max unchanged
                float ps = 0.f;
                #pragma unroll
                for (int j = 0; j < 4; ++j) { p[i][j] = expf(s[i][j] - mn); ps += p[i][j]; }
                #pragma unroll
                for (int off = 1; off < 16; off <<= 1) ps += __shfl_xor(ps, off);
                l_i[i] = l_i[i] * sc + ps;
                m_i[i] = mn;
                #pragma unroll
                for (int j = 0; j < 4; ++j) o[i][j] *= sc;
            }
            __syncthreads();                  // prior PV done reading Psh
            #pragma unroll
            for (int i = 0; i < 4; ++i) {     // P[q][k], key = ty&3
                f4 pv = { p[i][0], p[i][1], p[i][2], p[i][3] };
                *reinterpret_cast<f4*>(&Psh[((ty * 4 + i) << 6) + ((tx ^ (ty & 3)) << 2)]) = pv;
            }
            __syncthreads();
            // ---- PV: o[q][d] += P[q][k] * Xh[k][d] ----
            #pragma unroll 4
            for (int kk = 0; kk < 64; kk += 4) {
                f4 pa[4], vv[4];
                #pragma unroll
                for (int i = 0; i < 4; ++i)
                    pa[i] = *reinterpret_cast<const f4*>(
                        &Psh[((ty * 4 + i) << 6) + ((((kk >> 2) ^ (ty & 3))) << 2)]);
                #pragma unroll
                for (int j = 0; j < 4; ++j) {
                    int dv = (tx << 2) + j;
                    int keyk = (dv ^ (dv >> 2)) & 7;
                    vv[j] = *reinterpret_cast<const f4*>(
                        &XKT[(dv << 7) + ks + ((((kk >> 2) ^ keyk)) << 2)]);
                }
                #pragma unroll
                for (int i = 0; i < 4; ++i)
                    #pragma unroll
                    for (int j = 0; j < 4; ++j)
                        #pragma unroll
                        for (int t = 0; t < 4; ++t) o[i][j] += pa[i][t] * vv[j][t];
            }
        }
    }
    // epilogue: normalize and store head-major into y[b, q, h*64 + d]
    float* yb = y + ((size_t)b * S_ + qt0) * D_ + h * DK_;
    #pragma unroll
    for (int i = 0; i < 4; ++i) {
        float inv = 1.f / l_i[i];
        f4 ov = { o[i][0] * inv, o[i][1] * inv, o[i][2] * inv, o[i][3] * inv };
        *reinterpret_cast<f4*>(yb + (size_t)(ty * 4 + i) * D_ + (tx << 2)) = ov;
    }
}

// ---------------------------------------------------------------------------
// C[m,n] = sum_k A[m,k] * Bw[n,k]   (both row-major, K-inner "NT" GEMM)
// 64x64 tile, BK=32, 256 threads, 4x4 per thread. Staged transposed+swizzled.
__global__ __launch_bounds__(256, 4) void k_gemm(const float* __restrict__ A,
                                                 const float* __restrict__ Bw,
                                                 float* __restrict__ C, int K) {
    __shared__ __align__(16) float As[32 * 64];
    __shared__ __align__(16) float Bs[32 * 64];
    const int tid = threadIdx.x, tx = tid & 15, ty = tid >> 4;
    const int m0 = blockIdx.y << 6, n0 = blockIdx.x << 6;
    float acc[4][4] = {};

    for (int k0 = 0; k0 < K; k0 += 32) {
        __syncthreads();
        {
            int kc = tid & 7, rr = tid >> 3;      // rr 0..31
            #pragma unroll
            for (int pp = 0; pp < 2; ++pp) {
                int m = (pp << 5) + rr;
                f4 va = *reinterpret_cast<const f4*>(A  + (size_t)(m0 + m) * K + k0 + (kc << 2));
                f4 vb = *reinterpret_cast<const f4*>(Bw + (size_t)(n0 + m) * K + k0 + (kc << 2));
                #pragma unroll
                for (int e = 0; e < 4; ++e) {
                    int kk = (kc << 2) + e;
                    int key = (kk ^ (kk >> 2)) & 7;
                    int col = ((((m >> 2) ^ key) << 2) | (m & 3));
                    As[(kk << 6) + col] = va[e];
                    Bs[(kk << 6) + col] = vb[e];
                }
            }
        }
        __syncthreads();
        #pragma unroll
        for (int kk = 0; kk < 32; ++kk) {
            int key = (kk ^ (kk >> 2)) & 7;
            f4 a = *reinterpret_cast<const f4*>(&As[(kk << 6) + ((ty ^ key) << 2)]);
            f4 b = *reinterpret_cast<const f4*>(&Bs[(kk << 6) + ((tx ^ key) << 2)]);
            #pragma unroll
            for (int i = 0; i < 4; ++i)
                #pragma unroll
                for (int j = 0; j < 4; ++j) acc[i][j] += a[i] * b[j];
        }
    }
    #pragma unroll
    for (int i = 0; i < 4; ++i) {
        f4 cv = { acc[i][0], acc[i][1], acc[i][2], acc[i][3] };
        *reinterpret_cast<f4*>(C + (size_t)(m0 + ty * 4 + i) * D_ + n0 + (tx << 2)) = cv;
    }
}

// ---------------------------------------------------------------------------
// FFN fused: C[m,d] = sum_f relu( sum_n qo[m,n]*w1[f,n] ) * w2[d,f]
// A-tile computed on the fly from qo (kept in regs) + w1 (broadcast loads).
__global__ __launch_bounds__(256, 4) void k_ffn(const float* __restrict__ qo,
                                                const float* __restrict__ w1,
                                                const float* __restrict__ w2,
                                                float* __restrict__ C) {
    __shared__ __align__(16) float As[32 * 64];
    __shared__ __align__(16) float Bs[32 * 64];
    const int tid = threadIdx.x, tx = tid & 15, ty = tid >> 4;
    const int m0 = blockIdx.y << 6, n0 = blockIdx.x << 6;

    float qreg[4][8];                        // this thread's 4 q_out rows
    #pragma unroll
    for (int mi = 0; mi < 4; ++mi) {
        const float* qr = qo + (size_t)(m0 + (tx << 2) + mi) * NQ_;
        #pragma unroll
        for (int n = 0; n < 8; ++n) qreg[mi][n] = qr[n];
    }

    float acc[4][4] = {};
    for (int k0 = 0; k0 < F_; k0 += 32) {
        __syncthreads();
        {   // stage Bs from w2
            int kc = tid & 7, nr = tid >> 3;
            #pragma unroll
            for (int pp = 0; pp < 2; ++pp) {
                int n = (pp << 5) + nr;
                f4 v = *reinterpret_cast<const f4*>(w2 + (size_t)(n0 + n) * F_ + k0 + (kc << 2));
                #pragma unroll
                for (int e = 0; e < 4; ++e) {
                    int kk = (kc << 2) + e;
                    int key = (kk ^ (kk >> 2)) & 7;
                    Bs[(kk << 6) + ((((n >> 2) ^ key) << 2) | (n & 3))] = v[e];
                }
            }
        }
        {   // compute+stage As (relu(h)) : thread covers kk = 2ty..2ty+1, m = 4tx..4tx+3
            #pragma unroll
            for (int kki = 0; kki < 2; ++kki) {
                int kk = (ty << 1) + kki;
                const f4* w1r = reinterpret_cast<const f4*>(w1 + (size_t)(k0 + kk) * NQ_);
                f4 wa = w1r[0], wb = w1r[1];
                f4 av;
                #pragma unroll
                for (int mi = 0; mi < 4; ++mi) {
                    float h = qreg[mi][0]*wa[0] + qreg[mi][1]*wa[1] + qreg[mi][2]*wa[2] +
                              qreg[mi][3]*wa[3] + qreg[mi][4]*wb[0] + qreg[mi][5]*wb[1] +
                              qreg[mi][6]*wb[2] + qreg[mi][7]*wb[3];
                    av[mi] = fmaxf(h, 0.f);
                }
                int key = (kk ^ (kk >> 2)) & 7;
                *reinterpret_cast<f4*>(&As[(kk << 6) + ((tx ^ key) << 2)]) = av;
            }
        }
        __syncthreads();
        #pragma unroll
        for (int kk = 0; kk < 32; ++kk) {
            int key = (kk ^ (kk >> 2)) & 7;
            f4 a = *reinterpret_cast<const f4*>(&As[(kk << 6) + ((ty ^ key) << 2)]);
            f4 b = *reinterpret_cast<const f4*>(&Bs[(kk << 6) + ((tx ^ key) << 2)]);
            #pragma unroll
            for (int i = 0; i < 4; ++i)
                #pragma unroll
                for (int j = 0; j < 4; ++j) acc[i][j] += a[i] * b[j];
        }
    }
    #pragma unroll
    for (int i = 0; i < 4; ++i) {
        f4 cv = { acc[i][0], acc[i][1], acc[i][2], acc[i][3] };
        *reinterpret_cast<f4*>(C + (size_t)(m0 + ty * 4 + i) * D_ + n0 + (tx << 2)) = cv;
    }
}

// ---------------------------------------------------------------------------
// x = LayerNorm(x + z) * g + b  — one wave per 512-wide row, two-pass var
__global__ __launch_bounds__(256) void k_addln(float* __restrict__ x,
                                               const float* __restrict__ z,
                                               const float* __restrict__ g,
                                               const float* __restrict__ bb) {
    int row  = (blockIdx.x << 2) + (threadIdx.x >> 6);
    int lane = threadIdx.x & 63;
    float* xr = x + (size_t)row * D_;
    const float* zr = z + (size_t)row * D_;
    float v[8]; float s = 0.f;
    #pragma unroll
    for (int p = 0; p < 2; ++p) {
        f4 xv = *reinterpret_cast<const f4*>(xr + lane * 8 + p * 4);
        f4 zv = *reinterpret_cast<const f4*>(zr + lane * 8 + p * 4);
        #pragma unroll
        for (int e = 0; e < 4; ++e) { v[p * 4 + e] = xv[e] + zv[e]; s += v[p * 4 + e]; }
    }
    #pragma unroll
    for (int off = 1; off < 64; off <<= 1) s += __shfl_xor(s, off);
    float mean = s * (1.f / 512.f);
    float ss = 0.f;
    #pragma unroll
    for (int k = 0; k < 8; ++k) { float dv = v[k] - mean; ss += dv * dv; }
    #pragma unroll
    for (int off = 1; off < 64; off <<= 1) ss += __shfl_xor(ss, off);
    float rstd = 1.f / sqrtf(ss * (1.f / 512.f) + 1e-5f);
    #pragma unroll
    for (int p = 0; p < 2; ++p) {
        f4 gv = *reinterpret_cast<const f4*>(g  + lane * 8 + p * 4);
        f4 bv = *reinterpret_cast<const f4*>(bb + lane * 8 + p * 4);
        f4 ov;
        #pragma unroll
        for (int e = 0; e < 4; ++e) ov[e] = (v[p * 4 + e] - mean) * rstd * gv[e] + bv[e];
        *reinterpret_cast<f4*>(xr + lane * 8 + p * 4) = ov;
    }
}

// ---------------------------------------------------------------------------
// quantum FFN closed form: qo[t,n] = cos(x[t,n]) * cos(theta[n]),  n < 8
__global__ __launch_bounds__(256) void k_qo(const float* __restrict__ x,
                                            const float* __restrict__ th,
                                            float* __restrict__ qo) {
    int i = blockIdx.x * 256 + threadIdx.x;       // < B*S*NQ
    int t = i >> 3, n = i & 7;
    qo[i] = cosf(x[(size_t)t * D_ + n]) * cosf(th[n]);
}

// ---------------------------------------------------------------------------
// mean-pool partials over S chunks of 128
__global__ __launch_bounds__(512) void k_pool(const float* __restrict__ x,
                                              float* __restrict__ pp) {
    int b = blockIdx.y, ch = blockIdx.x, d = threadIdx.x;
    const float* xr = x + ((size_t)b * S_ + ch * 128) * D_ + d;
    float s = 0.f;
    #pragma unroll 8
    for (int i = 0; i < 128; ++i) s += xr[(size_t)i * D_];
    pp[((size_t)b * 4 + ch) * D_ + d] = s;
}

// head: out[b,c] = mean-pooled @ head_w^T + head_b
__global__ __launch_bounds__(64) void k_head(const float* __restrict__ pp,
                                             const float* __restrict__ hw,
                                             const float* __restrict__ hb,
                                             float* __restrict__ out) {
    int b = blockIdx.x >> 1, c = blockIdx.x & 1;
    int lane = threadIdx.x;
    float s = 0.f;
    #pragma unroll
    for (int d = lane; d < D_; d += 64) {
        float pv = pp[((size_t)b * 4 + 0) * D_ + d] + pp[((size_t)b * 4 + 1) * D_ + d] +
                   pp[((size_t)b * 4 + 2) * D_ + d] + pp[((size_t)b * 4 + 3) * D_ + d];
        s += pv * hw[(size_t)c * D_ + d];
    }
    #pragma unroll
    for (int off = 1; off < 64; off <<= 1) s += __shfl_xor(s, off);
    if (lane == 0) out[b * 2 + c] = s * (1.f / 512.f) + hb[c];
}

// ---------------------------------------------------------------------------
extern "C" void kernel_launch(void* const* d_in, const int* in_sizes, int n_in,
                              void* d_out, int out_size, void* d_ws, size_t ws_size,
                              hipStream_t stream) {
    const int*   tok = (const int*)  d_in[0];
    const float* emb = (const float*)d_in[1];
    const float* cw  = (const float*)d_in[2];
    const float* th  = (const float*)d_in[3];
    const float* w1  = (const float*)d_in[4];
    const float* w2  = (const float*)d_in[5];
    const float* g1  = (const float*)d_in[6];
    const float* b1  = (const float*)d_in[7];
    const float* g2  = (const float*)d_in[8];
    const float* b2  = (const float*)d_in[9];
    const float* hw  = (const float*)d_in[10];
    const float* hb  = (const float*)d_in[11];
    float* out = (float*)d_out;

    float* ws = (float*)d_ws;
    float* x  = ws;                    // [B*S, D]   16.8 MB
    float* y  = ws + 4194304;          // [B*S, D]   attn head outputs
    float* z  = ws + 8388608;          // [B*S, D]   gemm outputs
    float* qo = ws + 12582912;         // [B*S, 8]
    float* pp = ws + 12648448;         // [B, 4, D]  pool partials

    k_embed<<<B_ * S_, 128, 0, stream>>>(tok, emb, x);
    for (int l = 0; l < 2; ++l) {
        k_attn <<<dim3(8, H_, B_), 256, 0, stream>>>(x, y);
        k_gemm <<<dim3(8, 128),    256, 0, stream>>>(y, cw + (size_t)l * D_ * D_, z, D_);
        k_addln<<<2048,            256, 0, stream>>>(x, z, g1 + l * D_, b1 + l * D_);
        k_qo   <<<256,             256, 0, stream>>>(x, th + l * NQ_, qo);
        k_ffn  <<<dim3(8, 128),    256, 0, stream>>>(qo, w1 + (size_t)l * F_ * NQ_,
                                                     w2 + (size_t)l * D_ * F_, z);
        k_addln<<<2048,            256, 0, stream>>>(x, z, g2 + l * D_, b2 + l * D_);
    }
    k_pool<<<dim3(4, B_), 512, 0, stream>>>(x, pp);
    k_head<<<32, 64, 0, stream>>>(pp, hw, hb, out);
}

// Round 10
// 726.358 us; speedup vs baseline: 1.6900x; 1.6900x over previous
//
#include <hip/hip_runtime.h>
#include <hip/hip_bf16.h>
#include <math.h>

#define B_  16
#define S_  512
#define D_  512
#define H_  8
#define DK_ 64
#define F_  2048
#define NQ_ 8

typedef float f4   __attribute__((ext_vector_type(4)));
typedef short bf16x8 __attribute__((ext_vector_type(8)));   // 8 bf16 (4 VGPRs)
typedef float f32x4  __attribute__((ext_vector_type(4)));
typedef unsigned short us4 __attribute__((ext_vector_type(4)));
typedef unsigned short us8 __attribute__((ext_vector_type(8)));

__device__ inline unsigned short f2bf(float v) {
    __hip_bfloat16 b = __float2bfloat16(v);               // RNE
    return *reinterpret_cast<unsigned short*>(&b);
}

// ---------------------------------------------------------------------------
// embedding + sinusoidal positional encoding
__global__ __launch_bounds__(128) void k_embed(const int* __restrict__ tok,
                                               const float* __restrict__ emb,
                                               float* __restrict__ x) {
    int row = blockIdx.x;            // b*S + s
    int s   = row & (S_ - 1);
    int t   = tok[row];
    int d0  = threadIdx.x << 2;
    f4 v = *reinterpret_cast<const f4*>(emb + (size_t)t * D_ + d0);
    #pragma unroll
    for (int e = 0; e < 4; ++e) {
        int d = d0 + e;
        float freq = expf(-(float)(d & ~1) * (9.210340371976184f / 512.f));
        float arg  = (float)s * freq;
        v[e] += (d & 1) ? cosf(arg) : sinf(arg);
    }
    *reinterpret_cast<f4*>(x + (size_t)row * D_ + d0) = v;
}

// ---------------------------------------------------------------------------
// flash attention per (b, h, q-tile of 64) — fp32 VALU, verified r9 (absmax~0)
__global__ __launch_bounds__(256, 2) void k_attn(const float* __restrict__ x,
                                                 float* __restrict__ y) {
    __shared__ __align__(16) float QT [DK_ * 64];   // 16 KiB
    __shared__ __align__(16) float XKT[DK_ * 128];  // 32 KiB
    __shared__ __align__(16) float Psh[64 * 64];    // 16 KiB

    const int tid = threadIdx.x;
    const int tx  = tid & 15;
    const int ty  = tid >> 4;
    const int qt0 = blockIdx.x << 6;
    const int h   = blockIdx.y, b = blockIdx.z;
    const float* xb = x + (size_t)b * S_ * D_ + h * DK_;

    {
        int c = tid & 15, r = tid >> 4;
        #pragma unroll
        for (int p = 0; p < 4; ++p) {
            int q = p * 16 + r;
            f4 v = *reinterpret_cast<const f4*>(xb + (size_t)(qt0 + q) * D_ + (c << 2));
            #pragma unroll
            for (int e = 0; e < 4; ++e) {
                int d = (c << 2) + e;
                int key = (d ^ (d >> 2)) & 3;
                QT[(d << 6) + ((((q >> 2) ^ key) << 2) | (q & 3))] = v[e];
            }
        }
    }

    float o[4][4] = {};
    float m_i[4], l_i[4];
    #pragma unroll
    for (int i = 0; i < 4; ++i) { m_i[i] = -INFINITY; l_i[i] = 0.f; }

    for (int k0 = 0; k0 < S_; k0 += 128) {
        __syncthreads();
        {
            int c = tid & 15, r = tid >> 4;
            #pragma unroll
            for (int p = 0; p < 8; ++p) {
                int kk = p * 16 + r;
                f4 v = *reinterpret_cast<const f4*>(xb + (size_t)(k0 + kk) * D_ + (c << 2));
                #pragma unroll
                for (int e = 0; e < 4; ++e) {
                    int d = (c << 2) + e;
                    int key = (d ^ (d >> 2)) & 7;
                    XKT[(d << 7) + ((((kk >> 2) ^ key) << 2) | (kk & 3))] = v[e];
                }
            }
        }
        __syncthreads();

        #pragma unroll
        for (int sub = 0; sub < 2; ++sub) {
            const int ks = sub << 6;
            float s[4][4] = {};
            #pragma unroll 8
            for (int d = 0; d < 64; ++d) {
                int keyq = (d ^ (d >> 2)) & 3;
                int keyk = (d ^ (d >> 2)) & 7;
                f4 aq = *reinterpret_cast<const f4*>(&QT [(d << 6) + ((ty ^ keyq) << 2)]);
                f4 bk = *reinterpret_cast<const f4*>(&XKT[(d << 7) + ks + ((tx ^ keyk) << 2)]);
                #pragma unroll
                for (int i = 0; i < 4; ++i)
                    #pragma unroll
                    for (int j = 0; j < 4; ++j) s[i][j] += aq[i] * bk[j];
            }
            float p[4][4];
            #pragma unroll
            for (int i = 0; i < 4; ++i) {
                #pragma unroll
                for (int j = 0; j < 4; ++j) s[i][j] *= 0.125f;
                float mm = fmaxf(fmaxf(s[i][0], s[i][1]), fmaxf(s[i][2], s[i][3]));
                #pragma unroll
                for (int off = 1; off < 16; off <<= 1) mm = fmaxf(mm, __shfl_xor(mm, off));
                float mn = fmaxf(m_i[i], mm);
                float sc = expf(m_i[i] - mn);
                float ps = 0.f;
                #pragma unroll
                for (int j = 0; j < 4; ++j) { p[i][j] = expf(s[i][j] - mn); ps += p[i][j]; }
                #pragma unroll
                for (int off = 1; off < 16; off <<= 1) ps += __shfl_xor(ps, off);
                l_i[i] = l_i[i] * sc + ps;
                m_i[i] = mn;
                #pragma unroll
                for (int j = 0; j < 4; ++j) o[i][j] *= sc;
            }
            __syncthreads();
            #pragma unroll
            for (int i = 0; i < 4; ++i) {
                f4 pv = { p[i][0], p[i][1], p[i][2], p[i][3] };
                *reinterpret_cast<f4*>(&Psh[((ty * 4 + i) << 6) + ((tx ^ (ty & 3)) << 2)]) = pv;
            }
            __syncthreads();
            #pragma unroll 4
            for (int kk = 0; kk < 64; kk += 4) {
                f4 pa[4], vv[4];
                #pragma unroll
                for (int i = 0; i < 4; ++i)
                    pa[i] = *reinterpret_cast<const f4*>(
                        &Psh[((ty * 4 + i) << 6) + ((((kk >> 2) ^ (ty & 3))) << 2)]);
                #pragma unroll
                for (int j = 0; j < 4; ++j) {
                    int dv = (tx << 2) + j;
                    int keyk = (dv ^ (dv >> 2)) & 7;
                    vv[j] = *reinterpret_cast<const f4*>(
                        &XKT[(dv << 7) + ks + ((((kk >> 2) ^ keyk)) << 2)]);
                }
                #pragma unroll
                for (int i = 0; i < 4; ++i)
                    #pragma unroll
                    for (int j = 0; j < 4; ++j)
                        #pragma unroll
                        for (int t = 0; t < 4; ++t) o[i][j] += pa[i][t] * vv[j][t];
            }
        }
    }
    float* yb = y + ((size_t)b * S_ + qt0) * D_ + h * DK_;
    #pragma unroll
    for (int i = 0; i < 4; ++i) {
        float inv = 1.f / l_i[i];
        f4 ov = { o[i][0] * inv, o[i][1] * inv, o[i][2] * inv, o[i][3] * inv };
        *reinterpret_cast<f4*>(yb + (size_t)(ty * 4 + i) * D_ + (tx << 2)) = ov;
    }
}

// ---------------------------------------------------------------------------
// bf16 MFMA NT GEMM: C[m, n0+n] (row stride 512) = [C +] sum_k A[m,k]*B[n,k]
// A:[M,K] bf16 row-major, B:[N,K] bf16 row-major. Tile 128x64, BK=32, 4 waves,
// wave tile 64x32 (4x2 fragments of 16x16). LDS rows padded 32->40 elems so
// fragment b128 reads are a uniform 2 lanes/bank per quarter-wave (free).
// Correctness note: A/B k-grouping uses contiguous-8 per lane; any consistent
// bijection is exact (dot-product permutation invariance); C/D mapping
// col=lane&15,row=(lane>>4)*4+reg is the HW-verified one.
__global__ __launch_bounds__(256, 4) void k_gemm_bf(const unsigned short* __restrict__ A,
                                                    const unsigned short* __restrict__ Bw,
                                                    float* __restrict__ C,
                                                    int K, int accFlag) {
    __shared__ short Asb[128 * 40];
    __shared__ short Bsb[64 * 40];
    const int tid = threadIdx.x;
    const int l   = tid & 63;
    const int w   = tid >> 6;
    const int wr  = w >> 1, wc = w & 1;
    const int n0  = blockIdx.x << 6;
    const int m0  = blockIdx.y << 7;
    const int lr  = l & 15;
    const int lg  = l >> 4;

    f32x4 acc[4][2];
    #pragma unroll
    for (int i = 0; i < 4; ++i)
        #pragma unroll
        for (int j = 0; j < 2; ++j) acc[i][j] = (f32x4){0.f, 0.f, 0.f, 0.f};

    const int r  = tid >> 2, ch = tid & 3;
    for (int k0 = 0; k0 < K; k0 += 32) {
        __syncthreads();
        *reinterpret_cast<us8*>(&Asb[r * 40 + ch * 8]) =
            *reinterpret_cast<const us8*>(&A[(size_t)(m0 + r) * K + k0 + ch * 8]);
        *reinterpret_cast<us8*>(&Asb[(r + 64) * 40 + ch * 8]) =
            *reinterpret_cast<const us8*>(&A[(size_t)(m0 + r + 64) * K + k0 + ch * 8]);
        *reinterpret_cast<us8*>(&Bsb[r * 40 + ch * 8]) =
            *reinterpret_cast<const us8*>(&Bw[(size_t)(n0 + r) * K + k0 + ch * 8]);
        __syncthreads();

        bf16x8 af[4], bf[2];
        #pragma unroll
        for (int i = 0; i < 4; ++i)
            af[i] = *reinterpret_cast<const bf16x8*>(&Asb[(wr * 64 + i * 16 + lr) * 40 + lg * 8]);
        #pragma unroll
        for (int j = 0; j < 2; ++j)
            bf[j] = *reinterpret_cast<const bf16x8*>(&Bsb[(wc * 32 + j * 16 + lr) * 40 + lg * 8]);
        #pragma unroll
        for (int i = 0; i < 4; ++i)
            #pragma unroll
            for (int j = 0; j < 2; ++j)
                acc[i][j] = __builtin_amdgcn_mfma_f32_16x16x32_bf16(af[i], bf[j], acc[i][j], 0, 0, 0);
    }

    #pragma unroll
    for (int i = 0; i < 4; ++i)
        #pragma unroll
        for (int j = 0; j < 2; ++j)
            #pragma unroll
            for (int rg = 0; rg < 4; ++rg) {
                size_t off = (size_t)(m0 + wr * 64 + i * 16 + lg * 4 + rg) * 512
                             + n0 + wc * 32 + j * 16 + lr;
                float prev = accFlag ? C[off] : 0.f;
                C[off] = prev + acc[i][j][rg];
            }
}

// ---------------------------------------------------------------------------
// H half-tile: Hb[m, f] = bf16(relu(sum_n qo[m,n]*w1h[f,n])), f in [0,1024)
__global__ __launch_bounds__(256) void k_h(const float* __restrict__ qo,
                                           const float* __restrict__ w1h,
                                           unsigned short* __restrict__ Hb) {
    int f  = blockIdx.x * 256 + threadIdx.x;      // 0..1023
    int m0 = blockIdx.y * 64;
    f4 wa = *reinterpret_cast<const f4*>(&w1h[(size_t)f * 8]);
    f4 wb = *reinterpret_cast<const f4*>(&w1h[(size_t)f * 8 + 4]);
    for (int m = 0; m < 64; ++m) {
        const f4* q = reinterpret_cast<const f4*>(&qo[(size_t)(m0 + m) * 8]);
        f4 qa = q[0], qb = q[1];
        float hv = qa[0]*wa[0] + qa[1]*wa[1] + qa[2]*wa[2] + qa[3]*wa[3]
                 + qb[0]*wb[0] + qb[1]*wb[1] + qb[2]*wb[2] + qb[3]*wb[3];
        Hb[(size_t)(m0 + m) * 1024 + f] = f2bf(fmaxf(hv, 0.f));
    }
}

// ---------------------------------------------------------------------------
// fp32 -> bf16 contiguous convert, 4 elems/thread
__global__ __launch_bounds__(256) void k_cvt(const float* __restrict__ src,
                                             unsigned short* __restrict__ dst) {
    int i = (blockIdx.x * 256 + threadIdx.x) << 2;
    f4 v = *reinterpret_cast<const f4*>(&src[i]);
    us4 o;
    #pragma unroll
    for (int e = 0; e < 4; ++e) o[e] = f2bf(v[e]);
    *reinterpret_cast<us4*>(&dst[i]) = o;
}

// w2 half convert: dst[n,0..1024) = bf16(w2h[n*2048 + 0..1024))
__global__ __launch_bounds__(256) void k_cvtw2(const float* __restrict__ w2h,
                                               unsigned short* __restrict__ dst) {
    int n = blockIdx.x;                 // 0..511
    int j = threadIdx.x << 2;           // 0..1020
    f4 v = *reinterpret_cast<const f4*>(&w2h[(size_t)n * 2048 + j]);
    us4 o;
    #pragma unroll
    for (int e = 0; e < 4; ++e) o[e] = f2bf(v[e]);
    *reinterpret_cast<us4*>(&dst[(size_t)n * 1024 + j]) = o;
}

// ---------------------------------------------------------------------------
// x = LayerNorm(x + z) * g + b — one wave per row
__global__ __launch_bounds__(256) void k_addln(float* __restrict__ x,
                                               const float* __restrict__ z,
                                               const float* __restrict__ g,
                                               const float* __restrict__ bb) {
    int row  = (blockIdx.x << 2) + (threadIdx.x >> 6);
    int lane = threadIdx.x & 63;
    float* xr = x + (size_t)row * D_;
    const float* zr = z + (size_t)row * D_;
    float v[8]; float s = 0.f;
    #pragma unroll
    for (int p = 0; p < 2; ++p) {
        f4 xv = *reinterpret_cast<const f4*>(xr + lane * 8 + p * 4);
        f4 zv = *reinterpret_cast<const f4*>(zr + lane * 8 + p * 4);
        #pragma unroll
        for (int e = 0; e < 4; ++e) { v[p * 4 + e] = xv[e] + zv[e]; s += v[p * 4 + e]; }
    }
    #pragma unroll
    for (int off = 1; off < 64; off <<= 1) s += __shfl_xor(s, off);
    float mean = s * (1.f / 512.f);
    float ss = 0.f;
    #pragma unroll
    for (int k = 0; k < 8; ++k) { float dv = v[k] - mean; ss += dv * dv; }
    #pragma unroll
    for (int off = 1; off < 64; off <<= 1) ss += __shfl_xor(ss, off);
    float rstd = 1.f / sqrtf(ss * (1.f / 512.f) + 1e-5f);
    #pragma unroll
    for (int p = 0; p < 2; ++p) {
        f4 gv = *reinterpret_cast<const f4*>(g  + lane * 8 + p * 4);
        f4 bv = *reinterpret_cast<const f4*>(bb + lane * 8 + p * 4);
        f4 ov;
        #pragma unroll
        for (int e = 0; e < 4; ++e) ov[e] = (v[p * 4 + e] - mean) * rstd * gv[e] + bv[e];
        *reinterpret_cast<f4*>(xr + lane * 8 + p * 4) = ov;
    }
}

// ---------------------------------------------------------------------------
__global__ __launch_bounds__(256) void k_qo(const float* __restrict__ x,
                                            const float* __restrict__ th,
                                            float* __restrict__ qo) {
    int i = blockIdx.x * 256 + threadIdx.x;
    int t = i >> 3, n = i & 7;
    qo[i] = cosf(x[(size_t)t * D_ + n]) * cosf(th[n]);
}

__global__ __launch_bounds__(512) void k_pool(const float* __restrict__ x,
                                              float* __restrict__ pp) {
    int b = blockIdx.y, ch = blockIdx.x, d = threadIdx.x;
    const float* xr = x + ((size_t)b * S_ + ch * 128) * D_ + d;
    float s = 0.f;
    #pragma unroll 8
    for (int i = 0; i < 128; ++i) s += xr[(size_t)i * D_];
    pp[((size_t)b * 4 + ch) * D_ + d] = s;
}

__global__ __launch_bounds__(64) void k_head(const float* __restrict__ pp,
                                             const float* __restrict__ hw,
                                             const float* __restrict__ hb,
                                             float* __restrict__ out) {
    int b = blockIdx.x >> 1, c = blockIdx.x & 1;
    int lane = threadIdx.x;
    float s = 0.f;
    #pragma unroll
    for (int d = lane; d < D_; d += 64) {
        float pv = pp[((size_t)b * 4 + 0) * D_ + d] + pp[((size_t)b * 4 + 1) * D_ + d] +
                   pp[((size_t)b * 4 + 2) * D_ + d] + pp[((size_t)b * 4 + 3) * D_ + d];
        s += pv * hw[(size_t)c * D_ + d];
    }
    #pragma unroll
    for (int off = 1; off < 64; off <<= 1) s += __shfl_xor(s, off);
    if (lane == 0) out[b * 2 + c] = s * (1.f / 512.f) + hb[c];
}

// ---------------------------------------------------------------------------
extern "C" void kernel_launch(void* const* d_in, const int* in_sizes, int n_in,
                              void* d_out, int out_size, void* d_ws, size_t ws_size,
                              hipStream_t stream) {
    const int*   tok = (const int*)  d_in[0];
    const float* emb = (const float*)d_in[1];
    const float* cw  = (const float*)d_in[2];
    const float* th  = (const float*)d_in[3];
    const float* w1  = (const float*)d_in[4];
    const float* w2  = (const float*)d_in[5];
    const float* g1  = (const float*)d_in[6];
    const float* b1  = (const float*)d_in[7];
    const float* g2  = (const float*)d_in[8];
    const float* b2  = (const float*)d_in[9];
    const float* hw  = (const float*)d_in[10];
    const float* hb  = (const float*)d_in[11];
    float* out = (float*)d_out;

    float* ws = (float*)d_ws;
    float* x  = ws;                                  // [8192,512] f32
    float* y  = ws + 4194304;                        // attn out f32 (dead after cvt)
    float* z  = ws + 8388608;                        // gemm out f32
    float* qo = ws + 12582912;                       // [8192,8] f32
    float* pp = ws + 12648448;                       // [16,4,512] f32
    unsigned short* yb  = (unsigned short*)(ws + 12681216);  // [8192,512] bf16
    unsigned short* cwb = (unsigned short*)(ws + 14778368);  // [512,512]  bf16
    unsigned short* w2b = (unsigned short*)(ws + 14909440);  // [512,1024] bf16
    unsigned short* Hb  = (unsigned short*)y;                // [8192,1024] bf16 (aliases dead y)

    k_embed<<<B_ * S_, 128, 0, stream>>>(tok, emb, x);
    for (int l = 0; l < 2; ++l) {
        k_attn<<<dim3(8, H_, B_), 256, 0, stream>>>(x, y);
        k_cvt <<<4096, 256, 0, stream>>>(y, yb);                      // y -> bf16 (y dead after)
        k_cvt <<<256,  256, 0, stream>>>(cw + (size_t)l * D_ * D_, cwb);
        k_gemm_bf<<<dim3(8, 64), 256, 0, stream>>>(yb, cwb, z, 512, 0);
        k_addln<<<2048, 256, 0, stream>>>(x, z, g1 + l * D_, b1 + l * D_);
        k_qo  <<<256, 256, 0, stream>>>(x, th + l * NQ_, qo);
        for (int h = 0; h < 2; ++h) {
            k_h    <<<dim3(4, 128), 256, 0, stream>>>(qo, w1 + (size_t)l * F_ * NQ_ + h * 1024 * NQ_, Hb);
            k_cvtw2<<<512, 256, 0, stream>>>(w2 + (size_t)l * D_ * F_ + h * 1024, w2b);
            k_gemm_bf<<<dim3(8, 64), 256, 0, stream>>>(Hb, w2b, z, 1024, h);
        }
        k_addln<<<2048, 256, 0, stream>>>(x, z, g2 + l * D_, b2 + l * D_);
    }
    k_pool<<<dim3(4, B_), 512, 0, stream>>>(x, pp);
    k_head<<<32, 64, 0, stream>>>(pp, hw, hb, out);
}

// Round 11
// 557.121 us; speedup vs baseline: 2.2034x; 1.3038x over previous
//
#include <hip/hip_runtime.h>
#include <hip/hip_bf16.h>
#include <math.h>

#define B_  16
#define S_  512
#define D_  512
#define H_  8
#define DK_ 64
#define F_  2048
#define NQ_ 8

typedef float f4   __attribute__((ext_vector_type(4)));
typedef short bf16x8 __attribute__((ext_vector_type(8)));
typedef float f32x4  __attribute__((ext_vector_type(4)));
typedef unsigned short us4 __attribute__((ext_vector_type(4)));
typedef unsigned short us8 __attribute__((ext_vector_type(8)));

__device__ inline unsigned short f2bf(float v) {
    __hip_bfloat16 b = __float2bfloat16(v);               // RNE
    return *reinterpret_cast<unsigned short*>(&b);
}

// ---------------------------------------------------------------------------
// embedding + sinusoidal positional encoding (libm for PE fidelity)
__global__ __launch_bounds__(128) void k_embed(const int* __restrict__ tok,
                                               const float* __restrict__ emb,
                                               float* __restrict__ x) {
    int row = blockIdx.x;
    int s   = row & (S_ - 1);
    int t   = tok[row];
    int d0  = threadIdx.x << 2;
    f4 v = *reinterpret_cast<const f4*>(emb + (size_t)t * D_ + d0);
    #pragma unroll
    for (int e = 0; e < 4; ++e) {
        int d = d0 + e;
        float freq = expf(-(float)(d & ~1) * (9.210340371976184f / 512.f));
        float arg  = (float)s * freq;
        v[e] += (d & 1) ? cosf(arg) : sinf(arg);
    }
    *reinterpret_cast<f4*>(x + (size_t)row * D_ + d0) = v;
}

// ---------------------------------------------------------------------------
// bf16 MFMA flash attention. Block = (qtile 64, h, b), 4 waves; wave w owns
// q-rows [w*16, w*16+16) x all 512 keys (softmax wave-local). Per 64-key tile:
// QK^T NT-mfma (A=Q, B=X), online softmax (16-lane shfl groups), P->LDS bf16
// (wave-private), PV NT-mfma (A=P, B=XT staged via in-LDS pack2 transpose).
// Fragment conventions identical to the r10-verified k_gemm_bf.
__global__ __launch_bounds__(256, 4) void k_attn_bf(const float* __restrict__ x,
                                                    unsigned short* __restrict__ yb) {
    __shared__ short Qs [64 * 72];      // 9216 B
    __shared__ short Xs [64 * 72];      // 9216 B
    __shared__ short XTs[64 * 72];      // 9216 B
    __shared__ short Ps [4][16 * 72];   // 9216 B (per-wave)

    const int tid = threadIdx.x;
    const int l  = tid & 63, w = tid >> 6;
    const int lr = l & 15,  lg = l >> 4;
    const int qt0 = blockIdx.x << 6;
    const int h   = blockIdx.y, b = blockIdx.z;
    const float* xbase = x + (size_t)b * S_ * D_ + h * DK_;   // row stride D_

    // ---- stage Q (fp32 -> bf16) ----
    {
        int q = tid >> 2, c = tid & 3;
        const float* src = xbase + (size_t)(qt0 + q) * D_ + c * 16;
        f4 v0 = *reinterpret_cast<const f4*>(src);
        f4 v1 = *reinterpret_cast<const f4*>(src + 4);
        f4 v2 = *reinterpret_cast<const f4*>(src + 8);
        f4 v3 = *reinterpret_cast<const f4*>(src + 12);
        us8 o0, o1;
        #pragma unroll
        for (int e = 0; e < 4; ++e) {
            o0[e] = f2bf(v0[e]); o0[4 + e] = f2bf(v1[e]);
            o1[e] = f2bf(v2[e]); o1[4 + e] = f2bf(v3[e]);
        }
        *reinterpret_cast<us8*>(&Qs[q * 72 + c * 16])     = o0;
        *reinterpret_cast<us8*>(&Qs[q * 72 + c * 16 + 8]) = o1;
    }
    __syncthreads();
    bf16x8 aq[2];
    aq[0] = *reinterpret_cast<const bf16x8*>(&Qs[(w * 16 + lr) * 72 + lg * 8]);
    aq[1] = *reinterpret_cast<const bf16x8*>(&Qs[(w * 16 + lr) * 72 + 32 + lg * 8]);

    f32x4 o[4];
    #pragma unroll
    for (int j = 0; j < 4; ++j) o[j] = (f32x4){0.f, 0.f, 0.f, 0.f};
    float m_i[4], l_i[4];
    #pragma unroll
    for (int rg = 0; rg < 4; ++rg) { m_i[rg] = -INFINITY; l_i[rg] = 0.f; }

    for (int k0 = 0; k0 < S_; k0 += 64) {
        __syncthreads();                       // all waves done with Xs/XTs
        {   // stage X tile (fp32 -> bf16)
            int kk = tid >> 2, c = tid & 3;
            const float* src = xbase + (size_t)(k0 + kk) * D_ + c * 16;
            f4 v0 = *reinterpret_cast<const f4*>(src);
            f4 v1 = *reinterpret_cast<const f4*>(src + 4);
            f4 v2 = *reinterpret_cast<const f4*>(src + 8);
            f4 v3 = *reinterpret_cast<const f4*>(src + 12);
            us8 o0, o1;
            #pragma unroll
            for (int e = 0; e < 4; ++e) {
                o0[e] = f2bf(v0[e]); o0[4 + e] = f2bf(v1[e]);
                o1[e] = f2bf(v2[e]); o1[4 + e] = f2bf(v3[e]);
            }
            *reinterpret_cast<us8*>(&Xs[kk * 72 + c * 16])     = o0;
            *reinterpret_cast<us8*>(&Xs[kk * 72 + c * 16 + 8]) = o1;
        }
        __syncthreads();
        {   // transpose Xs -> XTs (pack 2 keys per b32 write, ~2-way banks)
            int d = tid & 63, g = tid >> 6;
            #pragma unroll
            for (int i = 0; i < 8; ++i) {
                int kp = g * 8 + i;            // key pair 0..31
                unsigned int v0 = (unsigned short)Xs[(2 * kp)     * 72 + d];
                unsigned int v1 = (unsigned short)Xs[(2 * kp + 1) * 72 + d];
                *reinterpret_cast<unsigned int*>(&XTs[d * 72 + 2 * kp]) =
                    v0 | (v1 << 16);
            }
        }
        __syncthreads();

        // ---- QK^T: s[j] = S[q 16][key j*16+lr], fp32 accum ----
        f32x4 s[4];
        #pragma unroll
        for (int j = 0; j < 4; ++j) s[j] = (f32x4){0.f, 0.f, 0.f, 0.f};
        #pragma unroll
        for (int ks = 0; ks < 2; ++ks)
            #pragma unroll
            for (int j = 0; j < 4; ++j) {
                bf16x8 bk = *reinterpret_cast<const bf16x8*>(
                    &Xs[(j * 16 + lr) * 72 + ks * 32 + lg * 8]);
                s[j] = __builtin_amdgcn_mfma_f32_16x16x32_bf16(aq[ks], bk, s[j], 0, 0, 0);
            }

        // ---- online softmax, rows rg (q = lg*4+rg), reduce over 16 lr-lanes ----
        #pragma unroll
        for (int rg = 0; rg < 4; ++rg) {
            float v0 = s[0][rg] * 0.125f, v1 = s[1][rg] * 0.125f;
            float v2 = s[2][rg] * 0.125f, v3 = s[3][rg] * 0.125f;
            float mm = fmaxf(fmaxf(v0, v1), fmaxf(v2, v3));
            #pragma unroll
            for (int off = 1; off < 16; off <<= 1) mm = fmaxf(mm, __shfl_xor(mm, off));
            float mn = fmaxf(m_i[rg], mm);
            float sc = __expf(m_i[rg] - mn);
            float p0 = __expf(v0 - mn), p1 = __expf(v1 - mn);
            float p2 = __expf(v2 - mn), p3 = __expf(v3 - mn);
            float ps = p0 + p1 + p2 + p3;
            #pragma unroll
            for (int off = 1; off < 16; off <<= 1) ps += __shfl_xor(ps, off);
            l_i[rg] = l_i[rg] * sc + ps;
            m_i[rg] = mn;
            #pragma unroll
            for (int j = 0; j < 4; ++j) o[j][rg] *= sc;
            short* pr = &Ps[w][(lg * 4 + rg) * 72];
            pr[lr]      = (short)f2bf(p0);
            pr[16 + lr] = (short)f2bf(p1);
            pr[32 + lr] = (short)f2bf(p2);
            pr[48 + lr] = (short)f2bf(p3);
        }

        // ---- PV: O[q][d] += P[q][key] * X[key][d]  (A=P, B=XT) ----
        #pragma unroll
        for (int ks = 0; ks < 2; ++ks) {
            bf16x8 pa = *reinterpret_cast<const bf16x8*>(
                &Ps[w][lr * 72 + ks * 32 + lg * 8]);
            #pragma unroll
            for (int j = 0; j < 4; ++j) {
                bf16x8 bv = *reinterpret_cast<const bf16x8*>(
                    &XTs[(j * 16 + lr) * 72 + ks * 32 + lg * 8]);
                o[j] = __builtin_amdgcn_mfma_f32_16x16x32_bf16(pa, bv, o[j], 0, 0, 0);
            }
        }
    }

    // ---- epilogue: normalize, store bf16 head-major ----
    unsigned short* yrow = yb + ((size_t)b * S_ + qt0 + w * 16) * D_ + h * DK_;
    #pragma unroll
    for (int rg = 0; rg < 4; ++rg) {
        float inv = 1.f / l_i[rg];
        int q = lg * 4 + rg;
        #pragma unroll
        for (int j = 0; j < 4; ++j)
            yrow[(size_t)q * D_ + j * 16 + lr] = f2bf(o[j][rg] * inv);
    }
}

// ---------------------------------------------------------------------------
// bf16 MFMA NT GEMM (verified r10): C[m, n0+n] (row stride 512) = [C+] A·B^T
__global__ __launch_bounds__(256, 4) void k_gemm_bf(const unsigned short* __restrict__ A,
                                                    const unsigned short* __restrict__ Bw,
                                                    float* __restrict__ C,
                                                    int K, int accFlag) {
    __shared__ short Asb[128 * 40];
    __shared__ short Bsb[64 * 40];
    const int tid = threadIdx.x;
    const int l   = tid & 63;
    const int w   = tid >> 6;
    const int wr  = w >> 1, wc = w & 1;
    const int n0  = blockIdx.x << 6;
    const int m0  = blockIdx.y << 7;
    const int lr  = l & 15;
    const int lg  = l >> 4;

    f32x4 acc[4][2];
    #pragma unroll
    for (int i = 0; i < 4; ++i)
        #pragma unroll
        for (int j = 0; j < 2; ++j) acc[i][j] = (f32x4){0.f, 0.f, 0.f, 0.f};

    const int r  = tid >> 2, ch = tid & 3;
    for (int k0 = 0; k0 < K; k0 += 32) {
        __syncthreads();
        *reinterpret_cast<us8*>(&Asb[r * 40 + ch * 8]) =
            *reinterpret_cast<const us8*>(&A[(size_t)(m0 + r) * K + k0 + ch * 8]);
        *reinterpret_cast<us8*>(&Asb[(r + 64) * 40 + ch * 8]) =
            *reinterpret_cast<const us8*>(&A[(size_t)(m0 + r + 64) * K + k0 + ch * 8]);
        *reinterpret_cast<us8*>(&Bsb[r * 40 + ch * 8]) =
            *reinterpret_cast<const us8*>(&Bw[(size_t)(n0 + r) * K + k0 + ch * 8]);
        __syncthreads();

        bf16x8 af[4], bf[2];
        #pragma unroll
        for (int i = 0; i < 4; ++i)
            af[i] = *reinterpret_cast<const bf16x8*>(&Asb[(wr * 64 + i * 16 + lr) * 40 + lg * 8]);
        #pragma unroll
        for (int j = 0; j < 2; ++j)
            bf[j] = *reinterpret_cast<const bf16x8*>(&Bsb[(wc * 32 + j * 16 + lr) * 40 + lg * 8]);
        #pragma unroll
        for (int i = 0; i < 4; ++i)
            #pragma unroll
            for (int j = 0; j < 2; ++j)
                acc[i][j] = __builtin_amdgcn_mfma_f32_16x16x32_bf16(af[i], bf[j], acc[i][j], 0, 0, 0);
    }

    #pragma unroll
    for (int i = 0; i < 4; ++i)
        #pragma unroll
        for (int j = 0; j < 2; ++j)
            #pragma unroll
            for (int rg = 0; rg < 4; ++rg) {
                size_t off = (size_t)(m0 + wr * 64 + i * 16 + lg * 4 + rg) * 512
                             + n0 + wc * 32 + j * 16 + lr;
                float prev = accFlag ? C[off] : 0.f;
                C[off] = prev + acc[i][j][rg];
            }
}

// ---------------------------------------------------------------------------
// Hb[m, f] = bf16(relu(qo[m]·w1h[f])), f in [0,1024). Coalesced us8 stores.
// grid (4, 512): block covers f in [bx*256, bx*256+256), m in [by*16, by*16+16)
__global__ __launch_bounds__(256) void k_h(const float* __restrict__ qo,
                                           const float* __restrict__ w1h,
                                           unsigned short* __restrict__ Hb) {
    int m  = blockIdx.y * 16 + (threadIdx.x >> 4);
    int f0 = blockIdx.x * 256 + (threadIdx.x & 15) * 16;
    const f4* q = reinterpret_cast<const f4*>(&qo[(size_t)m * 8]);
    f4 qa = q[0], qb = q[1];
    us8 o0, o1;
    #pragma unroll
    for (int i = 0; i < 16; ++i) {
        const f4* wr = reinterpret_cast<const f4*>(&w1h[(size_t)(f0 + i) * 8]);
        f4 wa = wr[0], wb = wr[1];
        float hv = qa[0]*wa[0] + qa[1]*wa[1] + qa[2]*wa[2] + qa[3]*wa[3]
                 + qb[0]*wb[0] + qb[1]*wb[1] + qb[2]*wb[2] + qb[3]*wb[3];
        unsigned short r = f2bf(fmaxf(hv, 0.f));
        if (i < 8) o0[i] = r; else o1[i - 8] = r;
    }
    *reinterpret_cast<us8*>(&Hb[(size_t)m * 1024 + f0])     = o0;
    *reinterpret_cast<us8*>(&Hb[(size_t)m * 1024 + f0 + 8]) = o1;
}

// ---------------------------------------------------------------------------
__global__ __launch_bounds__(256) void k_cvt(const float* __restrict__ src,
                                             unsigned short* __restrict__ dst) {
    int i = (blockIdx.x * 256 + threadIdx.x) << 2;
    f4 v = *reinterpret_cast<const f4*>(&src[i]);
    us4 o;
    #pragma unroll
    for (int e = 0; e < 4; ++e) o[e] = f2bf(v[e]);
    *reinterpret_cast<us4*>(&dst[i]) = o;
}

__global__ __launch_bounds__(256) void k_cvtw2(const float* __restrict__ w2h,
                                               unsigned short* __restrict__ dst) {
    int n = blockIdx.x;
    int j = threadIdx.x << 2;
    f4 v = *reinterpret_cast<const f4*>(&w2h[(size_t)n * 2048 + j]);
    us4 o;
    #pragma unroll
    for (int e = 0; e < 4; ++e) o[e] = f2bf(v[e]);
    *reinterpret_cast<us4*>(&dst[(size_t)n * 1024 + j]) = o;
}

// ---------------------------------------------------------------------------
__global__ __launch_bounds__(256) void k_addln(float* __restrict__ x,
                                               const float* __restrict__ z,
                                               const float* __restrict__ g,
                                               const float* __restrict__ bb) {
    int row  = (blockIdx.x << 2) + (threadIdx.x >> 6);
    int lane = threadIdx.x & 63;
    float* xr = x + (size_t)row * D_;
    const float* zr = z + (size_t)row * D_;
    float v[8]; float s = 0.f;
    #pragma unroll
    for (int p = 0; p < 2; ++p) {
        f4 xv = *reinterpret_cast<const f4*>(xr + lane * 8 + p * 4);
        f4 zv = *reinterpret_cast<const f4*>(zr + lane * 8 + p * 4);
        #pragma unroll
        for (int e = 0; e < 4; ++e) { v[p * 4 + e] = xv[e] + zv[e]; s += v[p * 4 + e]; }
    }
    #pragma unroll
    for (int off = 1; off < 64; off <<= 1) s += __shfl_xor(s, off);
    float mean = s * (1.f / 512.f);
    float ss = 0.f;
    #pragma unroll
    for (int k = 0; k < 8; ++k) { float dv = v[k] - mean; ss += dv * dv; }
    #pragma unroll
    for (int off = 1; off < 64; off <<= 1) ss += __shfl_xor(ss, off);
    float rstd = 1.f / sqrtf(ss * (1.f / 512.f) + 1e-5f);
    #pragma unroll
    for (int p = 0; p < 2; ++p) {
        f4 gv = *reinterpret_cast<const f4*>(g  + lane * 8 + p * 4);
        f4 bv = *reinterpret_cast<const f4*>(bb + lane * 8 + p * 4);
        f4 ov;
        #pragma unroll
        for (int e = 0; e < 4; ++e) ov[e] = (v[p * 4 + e] - mean) * rstd * gv[e] + bv[e];
        *reinterpret_cast<f4*>(xr + lane * 8 + p * 4) = ov;
    }
}

// ---------------------------------------------------------------------------
__global__ __launch_bounds__(256) void k_qo(const float* __restrict__ x,
                                            const float* __restrict__ th,
                                            float* __restrict__ qo) {
    int i = blockIdx.x * 256 + threadIdx.x;
    int t = i >> 3, n = i & 7;
    qo[i] = cosf(x[(size_t)t * D_ + n]) * cosf(th[n]);
}

__global__ __launch_bounds__(512) void k_pool(const float* __restrict__ x,
                                              float* __restrict__ pp) {
    int b = blockIdx.y, ch = blockIdx.x, d = threadIdx.x;
    const float* xr = x + ((size_t)b * S_ + ch * 128) * D_ + d;
    float s = 0.f;
    #pragma unroll 8
    for (int i = 0; i < 128; ++i) s += xr[(size_t)i * D_];
    pp[((size_t)b * 4 + ch) * D_ + d] = s;
}

__global__ __launch_bounds__(64) void k_head(const float* __restrict__ pp,
                                             const float* __restrict__ hw,
                                             const float* __restrict__ hb,
                                             float* __restrict__ out) {
    int b = blockIdx.x >> 1, c = blockIdx.x & 1;
    int lane = threadIdx.x;
    float s = 0.f;
    #pragma unroll
    for (int d = lane; d < D_; d += 64) {
        float pv = pp[((size_t)b * 4 + 0) * D_ + d] + pp[((size_t)b * 4 + 1) * D_ + d] +
                   pp[((size_t)b * 4 + 2) * D_ + d] + pp[((size_t)b * 4 + 3) * D_ + d];
        s += pv * hw[(size_t)c * D_ + d];
    }
    #pragma unroll
    for (int off = 1; off < 64; off <<= 1) s += __shfl_xor(s, off);
    if (lane == 0) out[b * 2 + c] = s * (1.f / 512.f) + hb[c];
}

// ---------------------------------------------------------------------------
extern "C" void kernel_launch(void* const* d_in, const int* in_sizes, int n_in,
                              void* d_out, int out_size, void* d_ws, size_t ws_size,
                              hipStream_t stream) {
    const int*   tok = (const int*)  d_in[0];
    const float* emb = (const float*)d_in[1];
    const float* cw  = (const float*)d_in[2];
    const float* th  = (const float*)d_in[3];
    const float* w1  = (const float*)d_in[4];
    const float* w2  = (const float*)d_in[5];
    const float* g1  = (const float*)d_in[6];
    const float* b1  = (const float*)d_in[7];
    const float* g2  = (const float*)d_in[8];
    const float* b2  = (const float*)d_in[9];
    const float* hw  = (const float*)d_in[10];
    const float* hb  = (const float*)d_in[11];
    float* out = (float*)d_out;

    float* ws = (float*)d_ws;
    float* x  = ws;                                  // [8192,512] f32
    float* z  = ws + 4194304;                        // [8192,512] f32
    float* qo = ws + 8388608;                        // [8192,8]   f32
    float* pp = ws + 8454144;                        // [16,4,512] f32
    unsigned short* yb  = (unsigned short*)(ws + 8486912);   // [8192,512]  bf16
    unsigned short* cwb = (unsigned short*)(ws + 10584064);  // [512,512]   bf16
    unsigned short* w2b = (unsigned short*)(ws + 10715136);  // [512,1024]  bf16
    unsigned short* Hb  = (unsigned short*)(ws + 10977280);  // [8192,1024] bf16

    k_embed<<<B_ * S_, 128, 0, stream>>>(tok, emb, x);
    for (int l = 0; l < 2; ++l) {
        k_attn_bf<<<dim3(8, H_, B_), 256, 0, stream>>>(x, yb);
        k_cvt <<<256, 256, 0, stream>>>(cw + (size_t)l * D_ * D_, cwb);
        k_gemm_bf<<<dim3(8, 64), 256, 0, stream>>>(yb, cwb, z, 512, 0);
        k_addln<<<2048, 256, 0, stream>>>(x, z, g1 + l * D_, b1 + l * D_);
        k_qo  <<<256, 256, 0, stream>>>(x, th + l * NQ_, qo);
        for (int hh = 0; hh < 2; ++hh) {
            k_h    <<<dim3(4, 512), 256, 0, stream>>>(qo, w1 + (size_t)l * F_ * NQ_ + hh * 1024 * NQ_, Hb);
            k_cvtw2<<<512, 256, 0, stream>>>(w2 + (size_t)l * D_ * F_ + hh * 1024, w2b);
            k_gemm_bf<<<dim3(8, 64), 256, 0, stream>>>(Hb, w2b, z, 1024, hh);
        }
        k_addln<<<2048, 256, 0, stream>>>(x, z, g2 + l * D_, b2 + l * D_);
    }
    k_pool<<<dim3(4, B_), 512, 0, stream>>>(x, pp);
    k_head<<<32, 64, 0, stream>>>(pp, hw, hb, out);
}